// Round 1
// baseline (494.422 us; speedup 1.0000x reference)
//
#include <hip/hip_runtime.h>
#include <math.h>

#define HW   262144   // 512*512
#define NCF  32
#define NB   8
#define KK   16384    // (R1-R0)^2
#define GAMMA 0.9f
#define BETA  0.5f

// ws float-offset layout
#define WS_C0SUM   0     // [8][32] sum over bg
#define WS_C1SUM   256   // [8][32] sum over fg
#define WS_R0SQ    512   // [8][32] sumsq over bg
#define WS_R1SQ    768   // [8][32] sumsq over fg
#define WS_SUP     1024  // [1] global sum of logp[idx, tgt] over sup set
#define WS_SELFNUM 1032  // [8]
#define WS_SELFDEN 1040  // [8]
#define WS_FNUM    1048  // [8]
#define WS_FDEN    1056  // [8]
#define WS_C0      1064  // [8][32] centroid means
#define WS_C1      1320  // [8][32]
#define WS_N0      1576  // [8]
#define WS_N1      1584  // [8]
#define WS_MASK_F  8192  // bg membership mask (bytes) starts at float offset 8192

__global__ __launch_bounds__(256) void scatter_bg(const int* __restrict__ bg,
                                                  unsigned char* __restrict__ mask) {
    int i = blockIdx.x * 256 + threadIdx.x;      // 0 .. NB*KK-1
    int n = i >> 14;
    mask[(size_t)n * HW + bg[i]] = 1;
}

// one block per (item, set, channel): sum and sumsq of gathered features
__global__ __launch_bounds__(256) void centroid_sums(const float* __restrict__ act,
                                                     const int* __restrict__ fg,
                                                     const int* __restrict__ bg,
                                                     float* __restrict__ ws) {
    int b = blockIdx.x;
    int c = b & 31;
    int s = (b >> 5) & 1;   // 0 = bg, 1 = fg
    int n = b >> 6;
    const int* idx = (s ? fg : bg) + n * KK;
    const float* plane = act + (size_t)(n * NCF + c) * HW;
    float sum = 0.f, sq = 0.f;
    for (int k = threadIdx.x * 4; k < KK; k += 1024) {
        int4 id = *(const int4*)(idx + k);
        float a0 = plane[id.x], a1 = plane[id.y], a2 = plane[id.z], a3 = plane[id.w];
        sum += (a0 + a1) + (a2 + a3);
        sq  += a0*a0 + a1*a1 + a2*a2 + a3*a3;
    }
    __shared__ float red[2][4];
    for (int m = 32; m >= 1; m >>= 1) { sum += __shfl_xor(sum, m); sq += __shfl_xor(sq, m); }
    int lane = threadIdx.x & 63, wid = threadIdx.x >> 6;
    if (lane == 0) { red[0][wid] = sum; red[1][wid] = sq; }
    __syncthreads();
    if (threadIdx.x == 0) {
        sum = red[0][0] + red[0][1] + red[0][2] + red[0][3];
        sq  = red[1][0] + red[1][1] + red[1][2] + red[1][3];
        ws[(s ? WS_C1SUM : WS_C0SUM) + n * 32 + c] = sum;
        ws[(s ? WS_R1SQ  : WS_R0SQ ) + n * 32 + c] = sq;
    }
}

__global__ __launch_bounds__(64) void finalize_centroids(float* __restrict__ ws) {
    int n = blockIdx.x;
    int c = threadIdx.x & 31;
    float c0 = ws[WS_C0SUM + n * 32 + c] * (1.0f / KK);
    float c1 = ws[WS_C1SUM + n * 32 + c] * (1.0f / KK);
    float r0sq = ws[WS_R0SQ + n * 32 + c];
    float r1sq = ws[WS_R1SQ + n * 32 + c];
    float s_t0 = c0 * c0 * r0sq;   // (c0[c]*rn0[c])^2
    float s_t1 = c1 * c1 * r1sq;
    float s_n0 = c0 * c0, s_n1 = c1 * c1, s_dot = c0 * c1;
    for (int m = 16; m >= 1; m >>= 1) {  // masks <=16 stay within 32-lane halves
        s_t0 += __shfl_xor(s_t0, m); s_t1 += __shfl_xor(s_t1, m);
        s_n0 += __shfl_xor(s_n0, m); s_n1 += __shfl_xor(s_n1, m);
        s_dot += __shfl_xor(s_dot, m);
    }
    if (threadIdx.x < 32) {
        ws[WS_C0 + n * 32 + c] = c0;
        ws[WS_C1 + n * 32 + c] = c1;
        if (c == 0) {
            float n0 = sqrtf(s_n0), n1 = sqrtf(s_n1);
            ws[WS_N0 + n] = n0;
            ws[WS_N1 + n] = n1;
            ws[WS_FNUM + n] = s_dot / (n0 * n1);
            ws[WS_FDEN + n] = (float)KK * s_n0 / sqrtf(s_t0)
                            + (float)KK * s_n1 / sqrtf(s_t1);
        }
    }
}

// full-pixel pass: sims, pseudo labels, self-CE, and fused sup-CE
__global__ __launch_bounds__(256) void main_pass(const float* __restrict__ act,
                                                 const float* __restrict__ pred,
                                                 const int* __restrict__ tgt,
                                                 const unsigned char* __restrict__ mask,
                                                 float* __restrict__ ws) {
    int n = blockIdx.x >> 8;                               // 256 blocks per item
    int base = ((blockIdx.x & 255) << 10) | (threadIdx.x << 2);
    const float* aplane = act + (size_t)n * NCF * HW + base;

    __shared__ float sc0[32], sc1[32];
    if (threadIdx.x < 32) {
        sc0[threadIdx.x] = ws[WS_C0 + n * 32 + threadIdx.x];
        sc1[threadIdx.x] = ws[WS_C1 + n * 32 + threadIdx.x];
    }
    __syncthreads();
    float n0 = ws[WS_N0 + n], n1 = ws[WS_N1 + n];

    float4 d0 = {0,0,0,0}, d1 = {0,0,0,0}, nr = {0,0,0,0};
#pragma unroll
    for (int c = 0; c < 32; ++c) {
        float4 a = *(const float4*)(aplane + (size_t)c * HW);
        float w0 = sc0[c], w1 = sc1[c];
        d0.x += w0 * a.x; d0.y += w0 * a.y; d0.z += w0 * a.z; d0.w += w0 * a.w;
        d1.x += w1 * a.x; d1.y += w1 * a.y; d1.z += w1 * a.z; d1.w += w1 * a.w;
        nr.x += a.x * a.x; nr.y += a.y * a.y; nr.z += a.z * a.z; nr.w += a.w * a.w;
    }

    float dd0[4] = {d0.x, d0.y, d0.z, d0.w};
    float dd1[4] = {d1.x, d1.y, d1.z, d1.w};
    float nn[4]  = {nr.x, nr.y, nr.z, nr.w};
    int4 tv = *(const int4*)(tgt + (size_t)n * HW + base);
    int tarr[4] = {tv.x, tv.y, tv.z, tv.w};
    uchar4 mv = *(const uchar4*)(mask + (size_t)n * HW + base);
    unsigned char marr[4] = {mv.x, mv.y, mv.z, mv.w};
    const float* pp = pred + (size_t)n * 2 * HW + base;
    float4 q0 = *(const float4*)pp;
    float4 q1 = *(const float4*)(pp + HW);
    float p0a[4] = {q0.x, q0.y, q0.z, q0.w};
    float p1a[4] = {q1.x, q1.y, q1.z, q1.w};

    float sups = 0.f, sn = 0.f, sd = 0.f;
    float g0 = GAMMA * n0, g1 = GAMMA * n1;
#pragma unroll
    for (int j = 0; j < 4; ++j) {
        float an = sqrtf(nn[j]);
        int pseudo = (dd1[j] > g1 * an) ? 1 : ((dd0[j] > g0 * an) ? 0 : 2);
        float mx = fmaxf(p0a[j], p1a[j]);
        float lse = mx + logf(expf(p0a[j] - mx) + expf(p1a[j] - mx));
        float lp0 = p0a[j] - lse, lp1 = p1a[j] - lse;
        bool isbg = marr[j] != 0;
        int tg = tarr[j];
        if (tg == 1 || isbg) sups += tg ? lp1 : lp0;
        if (tg == 0 && !isbg && pseudo != 2) { sn += (pseudo == 1) ? -lp1 : -lp0; sd += 1.0f; }
    }

    // block reduce 3 values
    __shared__ float red[3][4];
    for (int m = 32; m >= 1; m >>= 1) {
        sups += __shfl_xor(sups, m); sn += __shfl_xor(sn, m); sd += __shfl_xor(sd, m);
    }
    int lane = threadIdx.x & 63, wid = threadIdx.x >> 6;
    if (lane == 0) { red[0][wid] = sups; red[1][wid] = sn; red[2][wid] = sd; }
    __syncthreads();
    if (threadIdx.x == 0) {
        atomicAdd(&ws[WS_SUP],         red[0][0] + red[0][1] + red[0][2] + red[0][3]);
        atomicAdd(&ws[WS_SELFNUM + n], red[1][0] + red[1][1] + red[1][2] + red[1][3]);
        atomicAdd(&ws[WS_SELFDEN + n], red[2][0] + red[2][1] + red[2][2] + red[2][3]);
    }
}

__global__ __launch_bounds__(64) void final_combine(const float* __restrict__ ws,
                                                    const int* __restrict__ t_,
                                                    const int* __restrict__ T1_,
                                                    const int* __restrict__ T2_,
                                                    const int* __restrict__ lam_,
                                                    float* __restrict__ out) {
    if (threadIdx.x != 0) return;
    float sup = -ws[WS_SUP] / (float)(2 * KK);
    float self = 0.f, fn = 0.f, fd = 0.f;
    for (int n = 0; n < NB; ++n) {
        self += ws[WS_SELFNUM + n] / ws[WS_SELFDEN + n];  // 0/0 -> NaN, matches jnp
        fn += ws[WS_FNUM + n];
        fd += ws[WS_FDEN + n];
    }
    float fisher = fn / fd;
    int t = *t_, T1 = *T1_, T2 = *T2_;
    float lam = (float)*lam_;
    float res;
    if (t < T1) {
        res = sup;
    } else {
        float alpha = (t < T2) ? (float)(t - T1) * lam / (float)(T2 - T1) : lam;
        float loss = sup + alpha * self + BETA * fisher;
        bool bad = (self != self) || (fisher != fisher);
        res = bad ? sup : loss;
    }
    out[0] = res;
}

extern "C" void kernel_launch(void* const* d_in, const int* in_sizes, int n_in,
                              void* d_out, int out_size, void* d_ws, size_t ws_size,
                              hipStream_t stream) {
    const float* act  = (const float*)d_in[0];
    const float* pred = (const float*)d_in[1];
    const int*   tgt  = (const int*)d_in[2];
    // d_in[3] full_target unused by reference math
    const int*   fg   = (const int*)d_in[4];
    const int*   bg   = (const int*)d_in[5];
    const int*   t_   = (const int*)d_in[6];
    const int*   T1_  = (const int*)d_in[7];
    const int*   T2_  = (const int*)d_in[8];
    const int*   lam_ = (const int*)d_in[9];
    float* ws = (float*)d_ws;
    unsigned char* mask = (unsigned char*)d_ws + (size_t)WS_MASK_F * 4;
    float* out = (float*)d_out;

    hipMemsetAsync(d_ws, 0, (size_t)WS_MASK_F * 4 + (size_t)NB * HW, stream);
    hipLaunchKernelGGL(scatter_bg, dim3(NB * KK / 256), dim3(256), 0, stream, bg, mask);
    hipLaunchKernelGGL(centroid_sums, dim3(NB * 2 * NCF), dim3(256), 0, stream, act, fg, bg, ws);
    hipLaunchKernelGGL(finalize_centroids, dim3(NB), dim3(64), 0, stream, ws);
    hipLaunchKernelGGL(main_pass, dim3(NB * HW / 1024), dim3(256), 0, stream, act, pred, tgt, mask, ws);
    hipLaunchKernelGGL(final_combine, dim3(1), dim3(64), 0, stream, ws, t_, T1_, T2_, lam_, out);
}

// Round 2
// 469.630 us; speedup vs baseline: 1.0528x; 1.0528x over previous
//
#include <hip/hip_runtime.h>
#include <math.h>

#define HW   262144   // 512*512
#define NCF  32
#define NB   8
#define KK   16384    // (R1-R0)^2
#define GAMMA 0.9f
#define BETA  0.5f

// ws float-offset layout
#define WS_C0SUM   0     // [8][32] sum over bg
#define WS_C1SUM   256   // [8][32] sum over fg
#define WS_R0SQ    512   // [8][32] sumsq over bg
#define WS_R1SQ    768   // [8][32] sumsq over fg
#define WS_SUP     1024  // [1] global sum of logp[idx, tgt] over sup set
#define WS_SELFNUM 1032  // [8]
#define WS_SELFDEN 1040  // [8]
#define WS_FNUM    1048  // [8]
#define WS_FDEN    1056  // [8]
#define WS_C0      1064  // [8][32] centroid means
#define WS_C1      1320  // [8][32]
#define WS_N0      1576  // [8]
#define WS_N1      1584  // [8]
#define WS_CODE_F  8192  // per-pixel code bytes (0=other, 1=fg, 2=bg), float offset

// code[n][p] = (tgt==1) ? 1 : 0   (fg_idx == where(tgt==1) by construction)
__global__ __launch_bounds__(256) void build_code(const int* __restrict__ tgt,
                                                  unsigned char* __restrict__ code) {
    int i = blockIdx.x * 1024 + threadIdx.x * 4;   // over NB*HW
    int4 tv = *(const int4*)(tgt + i);
    uchar4 cd;
    cd.x = (tv.x == 1); cd.y = (tv.y == 1); cd.z = (tv.z == 1); cd.w = (tv.w == 1);
    *(uchar4*)(code + i) = cd;
}

// bg pixels are tgt==0 by construction, so plain store of 2 (bytes unique per thread)
__global__ __launch_bounds__(256) void scatter_bg(const int* __restrict__ bg,
                                                  unsigned char* __restrict__ code) {
    int i = blockIdx.x * 256 + threadIdx.x;      // 0 .. NB*KK-1
    int n = i >> 14;
    code[(size_t)n * HW + bg[i]] = 2;
}

// coalesced full-plane streaming: masked sum & sumsq per (item, channel)
__global__ __launch_bounds__(256) void centroid_pass(const float* __restrict__ act,
                                                     const unsigned char* __restrict__ code,
                                                     float* __restrict__ ws) {
    int chunk = blockIdx.x & 15;        // 16 chunks per plane
    int c = (blockIdx.x >> 4) & 31;
    int n = blockIdx.x >> 9;
    const float* plane = act + (size_t)(n * NCF + c) * HW + chunk * 16384;
    const unsigned char* cp = code + (size_t)n * HW + chunk * 16384;
    float s0 = 0.f, q0 = 0.f, s1 = 0.f, q1 = 0.f;
    for (int i = threadIdx.x * 4; i < 16384; i += 1024) {
        float4 a = *(const float4*)(plane + i);
        uchar4 cd = *(const uchar4*)(cp + i);
        float b;
        b = (cd.x == 2) ? 1.f : 0.f; s0 += b * a.x; q0 += b * a.x * a.x;
        b = (cd.x == 1) ? 1.f : 0.f; s1 += b * a.x; q1 += b * a.x * a.x;
        b = (cd.y == 2) ? 1.f : 0.f; s0 += b * a.y; q0 += b * a.y * a.y;
        b = (cd.y == 1) ? 1.f : 0.f; s1 += b * a.y; q1 += b * a.y * a.y;
        b = (cd.z == 2) ? 1.f : 0.f; s0 += b * a.z; q0 += b * a.z * a.z;
        b = (cd.z == 1) ? 1.f : 0.f; s1 += b * a.z; q1 += b * a.z * a.z;
        b = (cd.w == 2) ? 1.f : 0.f; s0 += b * a.w; q0 += b * a.w * a.w;
        b = (cd.w == 1) ? 1.f : 0.f; s1 += b * a.w; q1 += b * a.w * a.w;
    }
    __shared__ float red[4][4];
    for (int m = 32; m >= 1; m >>= 1) {
        s0 += __shfl_xor(s0, m); q0 += __shfl_xor(q0, m);
        s1 += __shfl_xor(s1, m); q1 += __shfl_xor(q1, m);
    }
    int lane = threadIdx.x & 63, wid = threadIdx.x >> 6;
    if (lane == 0) { red[0][wid] = s0; red[1][wid] = q0; red[2][wid] = s1; red[3][wid] = q1; }
    __syncthreads();
    if (threadIdx.x == 0) {
        atomicAdd(&ws[WS_C0SUM + n * 32 + c], red[0][0] + red[0][1] + red[0][2] + red[0][3]);
        atomicAdd(&ws[WS_R0SQ  + n * 32 + c], red[1][0] + red[1][1] + red[1][2] + red[1][3]);
        atomicAdd(&ws[WS_C1SUM + n * 32 + c], red[2][0] + red[2][1] + red[2][2] + red[2][3]);
        atomicAdd(&ws[WS_R1SQ  + n * 32 + c], red[3][0] + red[3][1] + red[3][2] + red[3][3]);
    }
}

__global__ __launch_bounds__(64) void finalize_centroids(float* __restrict__ ws) {
    int n = blockIdx.x;
    int c = threadIdx.x & 31;
    float c0 = ws[WS_C0SUM + n * 32 + c] * (1.0f / KK);
    float c1 = ws[WS_C1SUM + n * 32 + c] * (1.0f / KK);
    float r0sq = ws[WS_R0SQ + n * 32 + c];
    float r1sq = ws[WS_R1SQ + n * 32 + c];
    float s_t0 = c0 * c0 * r0sq;   // (c0[c]*rn0[c])^2
    float s_t1 = c1 * c1 * r1sq;
    float s_n0 = c0 * c0, s_n1 = c1 * c1, s_dot = c0 * c1;
    for (int m = 16; m >= 1; m >>= 1) {  // masks <=16 stay within 32-lane halves
        s_t0 += __shfl_xor(s_t0, m); s_t1 += __shfl_xor(s_t1, m);
        s_n0 += __shfl_xor(s_n0, m); s_n1 += __shfl_xor(s_n1, m);
        s_dot += __shfl_xor(s_dot, m);
    }
    if (threadIdx.x < 32) {
        ws[WS_C0 + n * 32 + c] = c0;
        ws[WS_C1 + n * 32 + c] = c1;
        if (c == 0) {
            float n0 = sqrtf(s_n0), n1 = sqrtf(s_n1);
            ws[WS_N0 + n] = n0;
            ws[WS_N1 + n] = n1;
            ws[WS_FNUM + n] = s_dot / (n0 * n1);
            ws[WS_FDEN + n] = (float)KK * s_n0 / sqrtf(s_t0)
                            + (float)KK * s_n1 / sqrtf(s_t1);
        }
    }
}

// full-pixel pass: sims, pseudo labels, self-CE, and fused sup-CE
__global__ __launch_bounds__(256) void main_pass(const float* __restrict__ act,
                                                 const float* __restrict__ pred,
                                                 const unsigned char* __restrict__ code,
                                                 float* __restrict__ ws) {
    int n = blockIdx.x >> 8;                               // 256 blocks per item
    int base = ((blockIdx.x & 255) << 10) | (threadIdx.x << 2);
    const float* aplane = act + (size_t)n * NCF * HW + base;

    __shared__ float sc0[32], sc1[32];
    if (threadIdx.x < 32) {
        sc0[threadIdx.x] = ws[WS_C0 + n * 32 + threadIdx.x];
        sc1[threadIdx.x] = ws[WS_C1 + n * 32 + threadIdx.x];
    }
    __syncthreads();
    float n0 = ws[WS_N0 + n], n1 = ws[WS_N1 + n];

    float4 d0 = {0,0,0,0}, d1 = {0,0,0,0}, nr = {0,0,0,0};
#pragma unroll
    for (int c = 0; c < 32; ++c) {
        float4 a = *(const float4*)(aplane + (size_t)c * HW);
        float w0 = sc0[c], w1 = sc1[c];
        d0.x += w0 * a.x; d0.y += w0 * a.y; d0.z += w0 * a.z; d0.w += w0 * a.w;
        d1.x += w1 * a.x; d1.y += w1 * a.y; d1.z += w1 * a.z; d1.w += w1 * a.w;
        nr.x += a.x * a.x; nr.y += a.y * a.y; nr.z += a.z * a.z; nr.w += a.w * a.w;
    }

    float dd0[4] = {d0.x, d0.y, d0.z, d0.w};
    float dd1[4] = {d1.x, d1.y, d1.z, d1.w};
    float nn[4]  = {nr.x, nr.y, nr.z, nr.w};
    uchar4 mv = *(const uchar4*)(code + (size_t)n * HW + base);
    unsigned char marr[4] = {mv.x, mv.y, mv.z, mv.w};
    const float* pp = pred + (size_t)n * 2 * HW + base;
    float4 q0 = *(const float4*)pp;
    float4 q1 = *(const float4*)(pp + HW);
    float p0a[4] = {q0.x, q0.y, q0.z, q0.w};
    float p1a[4] = {q1.x, q1.y, q1.z, q1.w};

    float sups = 0.f, sn = 0.f, sd = 0.f;
    float g0 = GAMMA * n0, g1 = GAMMA * n1;
#pragma unroll
    for (int j = 0; j < 4; ++j) {
        float an = sqrtf(nn[j]);
        int pseudo = (dd1[j] > g1 * an) ? 1 : ((dd0[j] > g0 * an) ? 0 : 2);
        float mx = fmaxf(p0a[j], p1a[j]);
        float lse = mx + logf(expf(p0a[j] - mx) + expf(p1a[j] - mx));
        float lp0 = p0a[j] - lse, lp1 = p1a[j] - lse;
        unsigned char cd = marr[j];   // 1=fg, 2=bg, 0=other
        if (cd != 0) sups += (cd == 1) ? lp1 : lp0;
        if (cd == 0 && pseudo != 2) { sn += (pseudo == 1) ? -lp1 : -lp0; sd += 1.0f; }
    }

    // block reduce 3 values
    __shared__ float red[3][4];
    for (int m = 32; m >= 1; m >>= 1) {
        sups += __shfl_xor(sups, m); sn += __shfl_xor(sn, m); sd += __shfl_xor(sd, m);
    }
    int lane = threadIdx.x & 63, wid = threadIdx.x >> 6;
    if (lane == 0) { red[0][wid] = sups; red[1][wid] = sn; red[2][wid] = sd; }
    __syncthreads();
    if (threadIdx.x == 0) {
        atomicAdd(&ws[WS_SUP],         red[0][0] + red[0][1] + red[0][2] + red[0][3]);
        atomicAdd(&ws[WS_SELFNUM + n], red[1][0] + red[1][1] + red[1][2] + red[1][3]);
        atomicAdd(&ws[WS_SELFDEN + n], red[2][0] + red[2][1] + red[2][2] + red[2][3]);
    }
}

__global__ __launch_bounds__(64) void final_combine(const float* __restrict__ ws,
                                                    const int* __restrict__ t_,
                                                    const int* __restrict__ T1_,
                                                    const int* __restrict__ T2_,
                                                    const int* __restrict__ lam_,
                                                    float* __restrict__ out) {
    if (threadIdx.x != 0) return;
    float sup = -ws[WS_SUP] / (float)(2 * KK);
    float self = 0.f, fn = 0.f, fd = 0.f;
    for (int n = 0; n < NB; ++n) {
        self += ws[WS_SELFNUM + n] / ws[WS_SELFDEN + n];  // 0/0 -> NaN, matches jnp
        fn += ws[WS_FNUM + n];
        fd += ws[WS_FDEN + n];
    }
    float fisher = fn / fd;
    int t = *t_, T1 = *T1_, T2 = *T2_;
    float lam = (float)*lam_;
    float res;
    if (t < T1) {
        res = sup;
    } else {
        float alpha = (t < T2) ? (float)(t - T1) * lam / (float)(T2 - T1) : lam;
        float loss = sup + alpha * self + BETA * fisher;
        bool bad = (self != self) || (fisher != fisher);
        res = bad ? sup : loss;
    }
    out[0] = res;
}

extern "C" void kernel_launch(void* const* d_in, const int* in_sizes, int n_in,
                              void* d_out, int out_size, void* d_ws, size_t ws_size,
                              hipStream_t stream) {
    const float* act  = (const float*)d_in[0];
    const float* pred = (const float*)d_in[1];
    const int*   tgt  = (const int*)d_in[2];
    // d_in[3] full_target unused by reference math
    const int*   fg   = (const int*)d_in[4];  (void)fg;  // fg == where(tgt==1)
    const int*   bg   = (const int*)d_in[5];
    const int*   t_   = (const int*)d_in[6];
    const int*   T1_  = (const int*)d_in[7];
    const int*   T2_  = (const int*)d_in[8];
    const int*   lam_ = (const int*)d_in[9];
    float* ws = (float*)d_ws;
    unsigned char* code = (unsigned char*)d_ws + (size_t)WS_CODE_F * 4;
    float* out = (float*)d_out;

    hipMemsetAsync(d_ws, 0, 8192, stream);  // zero accumulators only
    hipLaunchKernelGGL(build_code, dim3(NB * HW / 1024), dim3(256), 0, stream, tgt, code);
    hipLaunchKernelGGL(scatter_bg, dim3(NB * KK / 256), dim3(256), 0, stream, bg, code);
    hipLaunchKernelGGL(centroid_pass, dim3(NB * NCF * 16), dim3(256), 0, stream, act, code, ws);
    hipLaunchKernelGGL(finalize_centroids, dim3(NB), dim3(64), 0, stream, ws);
    hipLaunchKernelGGL(main_pass, dim3(NB * HW / 1024), dim3(256), 0, stream, act, pred, code, ws);
    hipLaunchKernelGGL(final_combine, dim3(1), dim3(64), 0, stream, ws, t_, T1_, T2_, lam_, out);
}